// Round 1
// baseline (631.570 us; speedup 1.0000x reference)
//
#include <hip/hip_runtime.h>
#include <math.h>

#define BATCH 8192
#define INSZ 784
#define SYS 1024
#define OUTSZ 10
#define NSTEP 100
#define HSTEP 0.01f
#define FFORCE 8.0f

// ---------------------------------------------------------------------------
// GEMM1: h[8192,1024] = x[8192,784] @ W1[1024,784]^T + b1
// fp32 LDS-tiled: BM=BN=64, BK=16, 256 threads, 4x4 micro-tile per thread.
// K = 784 = 49*16 exactly -> no tail handling.
// ---------------------------------------------------------------------------
#define BM 64
#define BN 64
#define BK 16
#define LDP (BM + 4)   // pad 4 -> 16B-aligned float4 rows, only 2-way bank alias (free)

__global__ __launch_bounds__(256, 4) void gemm1_kernel(
    const float* __restrict__ x, const float* __restrict__ W1,
    const float* __restrict__ b1, float* __restrict__ h)
{
    __shared__ float As[BK][LDP];
    __shared__ float Bs[BK][LDP];

    const int t   = threadIdx.x;
    const int bm  = blockIdx.y * BM;     // batch tile origin
    const int bn  = blockIdx.x * BN;     // system tile origin
    const int kx  = t & 15;              // k within tile (staging)
    const int row = t >> 4;              // 0..15 (staging)
    const int tx  = t & 15;              // n quad (compute)
    const int ty  = t >> 4;              // m quad (compute)

    float acc[4][4] = {{0.f}};

    for (int k0 = 0; k0 < INSZ; k0 += BK) {
        #pragma unroll
        for (int p = 0; p < 4; ++p) {
            int m = row + 16 * p;
            As[kx][m] = x [(size_t)(bm + m) * INSZ + k0 + kx];
            Bs[kx][m] = W1[(size_t)(bn + m) * INSZ + k0 + kx];
        }
        __syncthreads();
        #pragma unroll
        for (int k = 0; k < BK; ++k) {
            float4 a = *(const float4*)&As[k][ty * 4];
            float4 b = *(const float4*)&Bs[k][tx * 4];
            const float av[4] = {a.x, a.y, a.z, a.w};
            const float bv[4] = {b.x, b.y, b.z, b.w};
            #pragma unroll
            for (int i = 0; i < 4; ++i)
                #pragma unroll
                for (int j = 0; j < 4; ++j)
                    acc[i][j] = fmaf(av[i], bv[j], acc[i][j]);
        }
        __syncthreads();
    }

    const float4 bb = *(const float4*)&b1[bn + tx * 4];
    #pragma unroll
    for (int i = 0; i < 4; ++i) {
        float4 o;
        o.x = acc[i][0] + bb.x;
        o.y = acc[i][1] + bb.y;
        o.z = acc[i][2] + bb.z;
        o.w = acc[i][3] + bb.w;
        *(float4*)&h[(size_t)(bm + ty * 4 + i) * SYS + bn + tx * 4] = o;
    }
}

// ---------------------------------------------------------------------------
// RK4 Lorenz-96 (100 steps) + GEMM2 + log_softmax, fused.
// One wave (64 lanes) per batch row; each lane owns 16 contiguous elements.
// Circular halo (left 2, right 1) via __shfl each derivative eval.
// Block = 256 threads = 4 rows.
// ---------------------------------------------------------------------------
__global__ __launch_bounds__(256, 4) void rk4_kernel(
    const float* __restrict__ h, const float* __restrict__ W2,
    const float* __restrict__ b2, float* __restrict__ out)
{
    const int lane = threadIdx.x & 63;
    const int w    = threadIdx.x >> 6;
    const int row  = blockIdx.x * 4 + w;

    const int laneL = (lane + 63) & 63;
    const int laneR = (lane + 1) & 63;

    float X[16];
    {
        const float4* h4 = (const float4*)(h + (size_t)row * SYS) + lane * 4;
        float4 v0 = h4[0], v1 = h4[1], v2 = h4[2], v3 = h4[3];
        X[0]=v0.x; X[1]=v0.y; X[2]=v0.z; X[3]=v0.w;
        X[4]=v1.x; X[5]=v1.y; X[6]=v1.z; X[7]=v1.w;
        X[8]=v2.x; X[9]=v2.y; X[10]=v2.z; X[11]=v2.w;
        X[12]=v3.x; X[13]=v3.y; X[14]=v3.z; X[15]=v3.w;
    }

    // dX[j] = (X[j+1] - X[j-2]) * X[j-1] - X[j] + F   (circular over 1024)
    auto deriv = [&](const float (&y)[16], float (&k)[16]) {
        float left1  = __shfl(y[15], laneL);  // element j-1 for j = 16*lane
        float left2  = __shfl(y[14], laneL);  // element j-2 for j = 16*lane
        float right1 = __shfl(y[0],  laneR);  // element j+1 for j = 16*lane+15
        #pragma unroll
        for (int i = 0; i < 16; ++i) {
            float yp1 = (i < 15) ? y[i + 1] : right1;
            float ym1 = (i > 0)  ? y[i - 1] : left1;
            float ym2 = (i > 1)  ? y[i - 2] : ((i == 1) ? left1 : left2);
            k[i] = fmaf(yp1 - ym2, ym1, FFORCE - y[i]);
        }
    };

    float Y[16], K[16], acc[16];
    #pragma unroll 1
    for (int s = 0; s < NSTEP; ++s) {
        deriv(X, acc);                                   // k1
        #pragma unroll
        for (int i = 0; i < 16; ++i) Y[i] = fmaf(0.5f * HSTEP, acc[i], X[i]);
        deriv(Y, K);                                     // k2
        #pragma unroll
        for (int i = 0; i < 16; ++i) {
            acc[i] = fmaf(2.0f, K[i], acc[i]);
            Y[i]   = fmaf(0.5f * HSTEP, K[i], X[i]);
        }
        deriv(Y, K);                                     // k3
        #pragma unroll
        for (int i = 0; i < 16; ++i) {
            acc[i] = fmaf(2.0f, K[i], acc[i]);
            Y[i]   = fmaf(HSTEP, K[i], X[i]);
        }
        deriv(Y, K);                                     // k4
        #pragma unroll
        for (int i = 0; i < 16; ++i)
            X[i] = fmaf(HSTEP / 6.0f, acc[i] + K[i], X[i]);
    }

    // GEMM2 + log_softmax epilogue: logits[o] = sum_j X[j]*W2[o][j] + b2[o]
    float l[OUTSZ];
    #pragma unroll
    for (int o = 0; o < OUTSZ; ++o) {
        const float4* w4 = (const float4*)(W2 + (size_t)o * SYS) + lane * 4;
        float4 a = w4[0], b = w4[1], c = w4[2], d = w4[3];
        float s = 0.f;
        s = fmaf(X[0],  a.x, s); s = fmaf(X[1],  a.y, s);
        s = fmaf(X[2],  a.z, s); s = fmaf(X[3],  a.w, s);
        s = fmaf(X[4],  b.x, s); s = fmaf(X[5],  b.y, s);
        s = fmaf(X[6],  b.z, s); s = fmaf(X[7],  b.w, s);
        s = fmaf(X[8],  c.x, s); s = fmaf(X[9],  c.y, s);
        s = fmaf(X[10], c.z, s); s = fmaf(X[11], c.w, s);
        s = fmaf(X[12], d.x, s); s = fmaf(X[13], d.y, s);
        s = fmaf(X[14], d.z, s); s = fmaf(X[15], d.w, s);
        #pragma unroll
        for (int dlt = 1; dlt < 64; dlt <<= 1) s += __shfl_xor(s, dlt);
        l[o] = s + b2[o];
    }

    float m = l[0];
    #pragma unroll
    for (int o = 1; o < OUTSZ; ++o) m = fmaxf(m, l[o]);
    float ssum = 0.f;
    #pragma unroll
    for (int o = 0; o < OUTSZ; ++o) ssum += __expf(l[o] - m);
    const float lse = m + __logf(ssum);

    // lane o (o<10) stores l[o]-lse; select via cndmask chain (no LDS needed)
    float v = l[0] - lse;
    #pragma unroll
    for (int o = 1; o < OUTSZ; ++o)
        if (lane == o) v = l[o] - lse;
    if (lane < OUTSZ)
        out[(size_t)row * OUTSZ + lane] = v;
}

extern "C" void kernel_launch(void* const* d_in, const int* in_sizes, int n_in,
                              void* d_out, int out_size, void* d_ws, size_t ws_size,
                              hipStream_t stream)
{
    const float* x  = (const float*)d_in[0];
    const float* W1 = (const float*)d_in[1];
    const float* b1 = (const float*)d_in[2];
    const float* W2 = (const float*)d_in[3];
    const float* b2 = (const float*)d_in[4];
    float* out = (float*)d_out;
    float* h   = (float*)d_ws;   // 8192*1024*4 = 33.5 MB scratch

    dim3 g1(SYS / BN, BATCH / BM);   // 16 x 128 = 2048 blocks
    gemm1_kernel<<<g1, 256, 0, stream>>>(x, W1, b1, h);

    rk4_kernel<<<BATCH / 4, 256, 0, stream>>>(h, W2, b2, out);
}

// Round 2
// 505.190 us; speedup vs baseline: 1.2502x; 1.2502x over previous
//
#include <hip/hip_runtime.h>
#include <hip/hip_bf16.h>
#include <math.h>

#define BATCH 8192
#define INSZ 784
#define SYS 1024
#define OUTSZ 10
#define NSTEP 100
#define HSTEP 0.01f
#define FFORCE 8.0f

typedef short short8 __attribute__((ext_vector_type(8)));
typedef float float4v __attribute__((ext_vector_type(4)));

static __device__ __forceinline__ short f2bf(float x) {
    __hip_bfloat16 b = __float2bfloat16(x);   // RNE
    return __builtin_bit_cast(short, b);
}
static __device__ __forceinline__ float bf2f(short s) {
    unsigned int u = ((unsigned int)(unsigned short)s) << 16;
    return __builtin_bit_cast(float, u);
}

// ---------------------------------------------------------------------------
// GEMM1: h = x @ W1^T + b1 via split-bf16 MFMA (hi*hi + hi*lo + lo*hi).
// Tile 128x128, BK=32, 256 threads = 4 waves, each wave does 64x64 via
// 4x4 grid of 16x16x32 bf16 MFMA fragments. K padded 784->800 with zeros.
// LDS K-stride 40 bf16 (80B) -> only 2-way bank aliasing (free, m136).
// ---------------------------------------------------------------------------
#define BMg 128
#define BNg 128
#define BKg 32
#define LDK 40

__global__ __launch_bounds__(256, 3) void gemm1_kernel(
    const float* __restrict__ x, const float* __restrict__ W1,
    const float* __restrict__ b1, float* __restrict__ h)
{
    __shared__ short Ah[BMg * LDK], Al[BMg * LDK];
    __shared__ short Bh[BNg * LDK], Bl[BNg * LDK];

    const int t  = threadIdx.x;
    const int bm = blockIdx.y * BMg;
    const int bn = blockIdx.x * BNg;

    // staging role: thread handles one row, half of BK (16 floats)
    const int srow = t >> 1;
    const int kq   = (t & 1) * 16;

    // compute role
    const int wv   = t >> 6;
    const int lane = t & 63;
    const int lm   = lane & 15;
    const int q    = lane >> 4;
    const int rb   = (wv & 1) * 64;   // wave row block in tile
    const int cb   = (wv >> 1) * 64;  // wave col block in tile

    float4v acc[4][4];
    #pragma unroll
    for (int i = 0; i < 4; ++i)
        #pragma unroll
        for (int j = 0; j < 4; ++j) {
            acc[i][j][0] = 0.f; acc[i][j][1] = 0.f;
            acc[i][j][2] = 0.f; acc[i][j][3] = 0.f;
        }

    const float* xa0 = x  + (size_t)(bm + srow) * INSZ + kq;
    const float* wb0 = W1 + (size_t)(bn + srow) * INSZ + kq;

    for (int it = 0; it < 25; ++it) {
        const int k0 = it * BKg;
        // ---- stage fp32 -> split bf16 into LDS ----
        {
            const bool valid = (k0 + kq) < INSZ;   // whole 16-chunk valid or not
            float va[16], vb[16];
            if (valid) {
                #pragma unroll
                for (int p = 0; p < 4; ++p) {
                    float4 xv = ((const float4*)(xa0 + k0))[p];
                    float4 bv = ((const float4*)(wb0 + k0))[p];
                    va[4*p+0] = xv.x; va[4*p+1] = xv.y; va[4*p+2] = xv.z; va[4*p+3] = xv.w;
                    vb[4*p+0] = bv.x; vb[4*p+1] = bv.y; vb[4*p+2] = bv.z; vb[4*p+3] = bv.w;
                }
            } else {
                #pragma unroll
                for (int j = 0; j < 16; ++j) { va[j] = 0.f; vb[j] = 0.f; }
            }
            short8 ahi[2], alo[2], bhi[2], blo[2];
            #pragma unroll
            for (int j = 0; j < 16; ++j) {
                short h1 = f2bf(va[j]);
                short l1 = f2bf(va[j] - bf2f(h1));
                short h2 = f2bf(vb[j]);
                short l2 = f2bf(vb[j] - bf2f(h2));
                ahi[j >> 3][j & 7] = h1;  alo[j >> 3][j & 7] = l1;
                bhi[j >> 3][j & 7] = h2;  blo[j >> 3][j & 7] = l2;
            }
            const int base = srow * LDK + kq;
            *(short8*)&Ah[base] = ahi[0];  *(short8*)&Ah[base + 8] = ahi[1];
            *(short8*)&Al[base] = alo[0];  *(short8*)&Al[base + 8] = alo[1];
            *(short8*)&Bh[base] = bhi[0];  *(short8*)&Bh[base + 8] = bhi[1];
            *(short8*)&Bl[base] = blo[0];  *(short8*)&Bl[base + 8] = blo[1];
        }
        __syncthreads();

        // ---- MFMA ----
        short8 bhf[4], blf[4];
        #pragma unroll
        for (int fj = 0; fj < 4; ++fj) {
            const int off = (cb + fj * 16 + lm) * LDK + q * 8;
            bhf[fj] = *(const short8*)&Bh[off];
            blf[fj] = *(const short8*)&Bl[off];
        }
        #pragma unroll
        for (int fi = 0; fi < 4; ++fi) {
            const int off = (rb + fi * 16 + lm) * LDK + q * 8;
            short8 ah = *(const short8*)&Ah[off];
            short8 al = *(const short8*)&Al[off];
            #pragma unroll
            for (int fj = 0; fj < 4; ++fj) {
                acc[fi][fj] = __builtin_amdgcn_mfma_f32_16x16x32_bf16(ah, bhf[fj], acc[fi][fj], 0, 0, 0);
                acc[fi][fj] = __builtin_amdgcn_mfma_f32_16x16x32_bf16(ah, blf[fj], acc[fi][fj], 0, 0, 0);
                acc[fi][fj] = __builtin_amdgcn_mfma_f32_16x16x32_bf16(al, bhf[fj], acc[fi][fj], 0, 0, 0);
            }
        }
        __syncthreads();
    }

    // ---- epilogue: + b1, store fp32 ----
    #pragma unroll
    for (int fj = 0; fj < 4; ++fj) {
        const int col  = bn + cb + fj * 16 + lm;
        const float bias = b1[col];
        #pragma unroll
        for (int fi = 0; fi < 4; ++fi) {
            const int row0 = bm + rb + fi * 16 + q * 4;
            #pragma unroll
            for (int r = 0; r < 4; ++r)
                h[(size_t)(row0 + r) * SYS + col] = acc[fi][fj][r] + bias;
        }
    }
}

// ---------------------------------------------------------------------------
// RK4 Lorenz-96 (100 steps) + GEMM2 + log_softmax, fused.
// One wave per batch row, 16 contiguous elements/lane, halo via __shfl.
// In-place stage derivative (rolling prev1/prev2) -> live set X+acc+T = 48
// floats, fits 64 VGPRs without compiler shuffling.
// ---------------------------------------------------------------------------
__global__ __launch_bounds__(256, 4) void rk4_kernel(
    const float* __restrict__ hbuf, const float* __restrict__ W2,
    const float* __restrict__ b2, float* __restrict__ out)
{
    const int lane = threadIdx.x & 63;
    const int w    = threadIdx.x >> 6;
    const int row  = blockIdx.x * 4 + w;

    const int laneL = (lane + 63) & 63;
    const int laneR = (lane + 1) & 63;

    float X[16];
    {
        const float4* h4 = (const float4*)(hbuf + (size_t)row * SYS) + lane * 4;
        float4 v0 = h4[0], v1 = h4[1], v2 = h4[2], v3 = h4[3];
        X[0]=v0.x; X[1]=v0.y; X[2]=v0.z; X[3]=v0.w;
        X[4]=v1.x; X[5]=v1.y; X[6]=v1.z; X[7]=v1.w;
        X[8]=v2.x; X[9]=v2.y; X[10]=v2.z; X[11]=v2.w;
        X[12]=v3.x; X[13]=v3.y; X[14]=v3.z; X[15]=v3.w;
    }

    float acc[16], T[16];

    // in-place derivative: y <- L96'(y)
    auto deriv_ip = [&](float (&y)[16]) {
        float left1  = __shfl(y[15], laneL);
        float left2  = __shfl(y[14], laneL);
        float right1 = __shfl(y[0],  laneR);
        float p2 = left2, p1 = left1, cur = y[0];
        #pragma unroll
        for (int i = 0; i < 16; ++i) {
            float yp1 = (i < 15) ? y[i + 1] : right1;
            float nv  = fmaf(yp1 - p2, p1, FFORCE - cur);
            p2 = p1; p1 = cur;
            if (i < 15) cur = y[i + 1];
            y[i] = nv;
        }
    };

    #pragma unroll 1
    for (int s = 0; s < NSTEP; ++s) {
        // k1 = deriv(X), out-of-place into acc (X stays live)
        {
            float left1  = __shfl(X[15], laneL);
            float left2  = __shfl(X[14], laneL);
            float right1 = __shfl(X[0],  laneR);
            #pragma unroll
            for (int i = 0; i < 16; ++i) {
                float yp1 = (i < 15) ? X[i + 1] : right1;
                float ym1 = (i > 0)  ? X[i - 1] : left1;
                float ym2 = (i > 1)  ? X[i - 2] : ((i == 1) ? left1 : left2);
                acc[i] = fmaf(yp1 - ym2, ym1, FFORCE - X[i]);
            }
        }
        #pragma unroll
        for (int i = 0; i < 16; ++i) T[i] = fmaf(0.5f * HSTEP, acc[i], X[i]);
        deriv_ip(T);                                    // T = k2
        #pragma unroll
        for (int i = 0; i < 16; ++i) {
            acc[i] = fmaf(2.0f, T[i], acc[i]);
            T[i]   = fmaf(0.5f * HSTEP, T[i], X[i]);
        }
        deriv_ip(T);                                    // T = k3
        #pragma unroll
        for (int i = 0; i < 16; ++i) {
            acc[i] = fmaf(2.0f, T[i], acc[i]);
            T[i]   = fmaf(HSTEP, T[i], X[i]);
        }
        deriv_ip(T);                                    // T = k4
        #pragma unroll
        for (int i = 0; i < 16; ++i)
            X[i] = fmaf(HSTEP / 6.0f, acc[i] + T[i], X[i]);
    }

    // GEMM2 + log_softmax epilogue
    float l[OUTSZ];
    #pragma unroll
    for (int o = 0; o < OUTSZ; ++o) {
        const float4* w4 = (const float4*)(W2 + (size_t)o * SYS) + lane * 4;
        float4 a = w4[0], b = w4[1], c = w4[2], d = w4[3];
        float s = 0.f;
        s = fmaf(X[0],  a.x, s); s = fmaf(X[1],  a.y, s);
        s = fmaf(X[2],  a.z, s); s = fmaf(X[3],  a.w, s);
        s = fmaf(X[4],  b.x, s); s = fmaf(X[5],  b.y, s);
        s = fmaf(X[6],  b.z, s); s = fmaf(X[7],  b.w, s);
        s = fmaf(X[8],  c.x, s); s = fmaf(X[9],  c.y, s);
        s = fmaf(X[10], c.z, s); s = fmaf(X[11], c.w, s);
        s = fmaf(X[12], d.x, s); s = fmaf(X[13], d.y, s);
        s = fmaf(X[14], d.z, s); s = fmaf(X[15], d.w, s);
        #pragma unroll
        for (int dlt = 1; dlt < 64; dlt <<= 1) s += __shfl_xor(s, dlt);
        l[o] = s + b2[o];
    }

    float m = l[0];
    #pragma unroll
    for (int o = 1; o < OUTSZ; ++o) m = fmaxf(m, l[o]);
    float ssum = 0.f;
    #pragma unroll
    for (int o = 0; o < OUTSZ; ++o) ssum += __expf(l[o] - m);
    const float lse = m + __logf(ssum);

    float v = l[0] - lse;
    #pragma unroll
    for (int o = 1; o < OUTSZ; ++o)
        if (lane == o) v = l[o] - lse;
    if (lane < OUTSZ)
        out[(size_t)row * OUTSZ + lane] = v;
}

extern "C" void kernel_launch(void* const* d_in, const int* in_sizes, int n_in,
                              void* d_out, int out_size, void* d_ws, size_t ws_size,
                              hipStream_t stream)
{
    const float* x  = (const float*)d_in[0];
    const float* W1 = (const float*)d_in[1];
    const float* b1 = (const float*)d_in[2];
    const float* W2 = (const float*)d_in[3];
    const float* b2 = (const float*)d_in[4];
    float* out = (float*)d_out;
    float* h   = (float*)d_ws;   // 8192*1024*4 = 33.5 MB scratch

    dim3 g1(SYS / BNg, BATCH / BMg);   // 8 x 64 = 512 blocks
    gemm1_kernel<<<g1, 256, 0, stream>>>(x, W1, b1, h);

    rk4_kernel<<<BATCH / 4, 256, 0, stream>>>(h, W2, b2, out);
}

// Round 4
// 454.701 us; speedup vs baseline: 1.3890x; 1.1110x over previous
//
#include <hip/hip_runtime.h>
#include <hip/hip_bf16.h>
#include <math.h>

#define BATCH 8192
#define INSZ 784
#define SYS 1024
#define OUTSZ 10
#define NSTEP 100
#define HSTEP 0.01f
#define FFORCE 8.0f

typedef short short8 __attribute__((ext_vector_type(8)));
typedef float float4v __attribute__((ext_vector_type(4)));
typedef float v2f __attribute__((ext_vector_type(2)));

static __device__ __forceinline__ short f2bf(float x) {
    __hip_bfloat16 b = __float2bfloat16(x);   // RNE
    return __builtin_bit_cast(short, b);
}
static __device__ __forceinline__ float bf2f(short s) {
    unsigned int u = ((unsigned int)(unsigned short)s) << 16;
    return __builtin_bit_cast(float, u);
}

static __device__ __forceinline__ v2f pkfma(v2f a, v2f b, v2f c) {
    return __builtin_elementwise_fma(a, b, c);
}
static __device__ __forceinline__ v2f mk2(float x, float y) {
    v2f r; r.x = x; r.y = y; return r;
}
static __device__ __forceinline__ v2f swp(v2f v) {
    return __builtin_shufflevector(v, v, 1, 0);
}
static __device__ __forceinline__ v2f sh2(v2f v, int ln) {
    v2f r; r.x = __shfl(v.x, ln); r.y = __shfl(v.y, ln); return r;
}

// ---------------------------------------------------------------------------
// GEMM1 (unchanged from round 2): h = x @ W1^T + b1, split-bf16 MFMA.
// ---------------------------------------------------------------------------
#define BMg 128
#define BNg 128
#define BKg 32
#define LDK 40

__global__ __launch_bounds__(256, 3) void gemm1_kernel(
    const float* __restrict__ x, const float* __restrict__ W1,
    const float* __restrict__ b1, float* __restrict__ h)
{
    __shared__ short Ah[BMg * LDK], Al[BMg * LDK];
    __shared__ short Bh[BNg * LDK], Bl[BNg * LDK];

    const int t  = threadIdx.x;
    const int bm = blockIdx.y * BMg;
    const int bn = blockIdx.x * BNg;

    const int srow = t >> 1;
    const int kq   = (t & 1) * 16;

    const int wv   = t >> 6;
    const int lane = t & 63;
    const int lm   = lane & 15;
    const int q    = lane >> 4;
    const int rb   = (wv & 1) * 64;
    const int cb   = (wv >> 1) * 64;

    float4v acc[4][4];
    #pragma unroll
    for (int i = 0; i < 4; ++i)
        #pragma unroll
        for (int j = 0; j < 4; ++j) {
            acc[i][j][0] = 0.f; acc[i][j][1] = 0.f;
            acc[i][j][2] = 0.f; acc[i][j][3] = 0.f;
        }

    const float* xa0 = x  + (size_t)(bm + srow) * INSZ + kq;
    const float* wb0 = W1 + (size_t)(bn + srow) * INSZ + kq;

    for (int it = 0; it < 25; ++it) {
        const int k0 = it * BKg;
        {
            const bool valid = (k0 + kq) < INSZ;
            float va[16], vb[16];
            if (valid) {
                #pragma unroll
                for (int p = 0; p < 4; ++p) {
                    float4 xv = ((const float4*)(xa0 + k0))[p];
                    float4 bv = ((const float4*)(wb0 + k0))[p];
                    va[4*p+0] = xv.x; va[4*p+1] = xv.y; va[4*p+2] = xv.z; va[4*p+3] = xv.w;
                    vb[4*p+0] = bv.x; vb[4*p+1] = bv.y; vb[4*p+2] = bv.z; vb[4*p+3] = bv.w;
                }
            } else {
                #pragma unroll
                for (int j = 0; j < 16; ++j) { va[j] = 0.f; vb[j] = 0.f; }
            }
            short8 ahi[2], alo[2], bhi[2], blo[2];
            #pragma unroll
            for (int j = 0; j < 16; ++j) {
                short h1 = f2bf(va[j]);
                short l1 = f2bf(va[j] - bf2f(h1));
                short h2 = f2bf(vb[j]);
                short l2 = f2bf(vb[j] - bf2f(h2));
                ahi[j >> 3][j & 7] = h1;  alo[j >> 3][j & 7] = l1;
                bhi[j >> 3][j & 7] = h2;  blo[j >> 3][j & 7] = l2;
            }
            const int base = srow * LDK + kq;
            *(short8*)&Ah[base] = ahi[0];  *(short8*)&Ah[base + 8] = ahi[1];
            *(short8*)&Al[base] = alo[0];  *(short8*)&Al[base + 8] = alo[1];
            *(short8*)&Bh[base] = bhi[0];  *(short8*)&Bh[base + 8] = bhi[1];
            *(short8*)&Bl[base] = blo[0];  *(short8*)&Bl[base + 8] = blo[1];
        }
        __syncthreads();

        short8 bhf[4], blf[4];
        #pragma unroll
        for (int fj = 0; fj < 4; ++fj) {
            const int off = (cb + fj * 16 + lm) * LDK + q * 8;
            bhf[fj] = *(const short8*)&Bh[off];
            blf[fj] = *(const short8*)&Bl[off];
        }
        #pragma unroll
        for (int fi = 0; fi < 4; ++fi) {
            const int off = (rb + fi * 16 + lm) * LDK + q * 8;
            short8 ah = *(const short8*)&Ah[off];
            short8 al = *(const short8*)&Al[off];
            #pragma unroll
            for (int fj = 0; fj < 4; ++fj) {
                acc[fi][fj] = __builtin_amdgcn_mfma_f32_16x16x32_bf16(ah, bhf[fj], acc[fi][fj], 0, 0, 0);
                acc[fi][fj] = __builtin_amdgcn_mfma_f32_16x16x32_bf16(ah, blf[fj], acc[fi][fj], 0, 0, 0);
                acc[fi][fj] = __builtin_amdgcn_mfma_f32_16x16x32_bf16(al, bhf[fj], acc[fi][fj], 0, 0, 0);
            }
        }
        __syncthreads();
    }

    #pragma unroll
    for (int fj = 0; fj < 4; ++fj) {
        const int col  = bn + cb + fj * 16 + lm;
        const float bias = b1[col];
        #pragma unroll
        for (int fi = 0; fi < 4; ++fi) {
            const int row0 = bm + rb + fi * 16 + q * 4;
            #pragma unroll
            for (int r = 0; r < 4; ++r)
                h[(size_t)(row0 + r) * SYS + col] = acc[fi][fj][r] + bias;
        }
    }
}

// ---------------------------------------------------------------------------
// RK4 Lorenz-96 + GEMM2 + log_softmax, packed-fp32 (v_pk_fma_f32) version.
// Pairing: pair p = (y[p], y[p+512]), p in [0,512). The +1 element shift maps
// pair p -> pair p+1 uniformly; the circular wrap carries a component swap
// (pair 512 == swap(pair 0)), applied only at lane 0 / lane 63 via cndmask.
// Lane L owns pairs 8L..8L+7 -> 8 v2f of state; halos via 2 shuffles each.
// Per step: ~176 packed VALU + 24 DS vs ~310 scalar VALU before.
// ---------------------------------------------------------------------------
__global__ __launch_bounds__(256, 4) void rk4_kernel(
    const float* __restrict__ hbuf, const float* __restrict__ W2,
    const float* __restrict__ b2, float* __restrict__ out)
{
    const int lane = threadIdx.x & 63;
    const int w    = threadIdx.x >> 6;
    const int row  = blockIdx.x * 4 + w;

    const int laneL = (lane + 63) & 63;
    const int laneR = (lane + 1) & 63;
    const bool atL  = (lane == 0);
    const bool atR  = (lane == 63);

    v2f X[8];
    {
        const float4* b4 = (const float4*)(hbuf + (size_t)row * SYS);
        float4 a0 = b4[lane * 2], a1 = b4[lane * 2 + 1];
        float4 c0 = b4[128 + lane * 2], c1 = b4[129 + lane * 2];
        X[0] = mk2(a0.x, c0.x); X[1] = mk2(a0.y, c0.y);
        X[2] = mk2(a0.z, c0.z); X[3] = mk2(a0.w, c0.w);
        X[4] = mk2(a1.x, c1.x); X[5] = mk2(a1.y, c1.y);
        X[6] = mk2(a1.z, c1.z); X[7] = mk2(a1.w, c1.w);
    }

    const v2f Fv = mk2(FFORCE, FFORCE);
    v2f acc[8], T[8];

    // in-place derivative on y[8]
    auto deriv_ip = [&](v2f (&y)[8]) {
        v2f r1 = sh2(y[0], laneR);  r1 = atR ? swp(r1) : r1;
        v2f l1 = sh2(y[7], laneL);  l1 = atL ? swp(l1) : l1;
        v2f l2 = sh2(y[6], laneL);  l2 = atL ? swp(l2) : l2;
        v2f p2 = l2, p1 = l1, cur = y[0];
        #pragma unroll
        for (int i = 0; i < 8; ++i) {
            v2f yp1 = (i < 7) ? y[i + 1] : r1;
            v2f nv  = pkfma(yp1 - p2, p1, Fv - cur);
            p2 = p1; p1 = cur;
            if (i < 7) cur = y[i + 1];
            y[i] = nv;
        }
    };

    const v2f c_half = mk2(0.5f * HSTEP, 0.5f * HSTEP);
    const v2f c_full = mk2(HSTEP, HSTEP);
    const v2f c_two  = mk2(2.0f, 2.0f);
    const v2f c_six  = mk2(HSTEP / 6.0f, HSTEP / 6.0f);

    #pragma unroll 1
    for (int s = 0; s < NSTEP; ++s) {
        // k1 = deriv(X) out-of-place into acc (X stays live)
        {
            v2f r1 = sh2(X[0], laneR);  r1 = atR ? swp(r1) : r1;
            v2f l1 = sh2(X[7], laneL);  l1 = atL ? swp(l1) : l1;
            v2f l2 = sh2(X[6], laneL);  l2 = atL ? swp(l2) : l2;
            #pragma unroll
            for (int i = 0; i < 8; ++i) {
                v2f yp1 = (i < 7) ? X[i + 1] : r1;
                v2f ym1 = (i > 0) ? X[i - 1] : l1;
                v2f ym2 = (i > 1) ? X[i - 2] : ((i == 1) ? l1 : l2);
                acc[i] = pkfma(yp1 - ym2, ym1, Fv - X[i]);
            }
        }
        #pragma unroll
        for (int i = 0; i < 8; ++i) T[i] = pkfma(c_half, acc[i], X[i]);
        deriv_ip(T);                                    // T = k2
        #pragma unroll
        for (int i = 0; i < 8; ++i) {
            acc[i] = pkfma(c_two, T[i], acc[i]);
            T[i]   = pkfma(c_half, T[i], X[i]);
        }
        deriv_ip(T);                                    // T = k3
        #pragma unroll
        for (int i = 0; i < 8; ++i) {
            acc[i] = pkfma(c_two, T[i], acc[i]);
            T[i]   = pkfma(c_full, T[i], X[i]);
        }
        deriv_ip(T);                                    // T = k4
        #pragma unroll
        for (int i = 0; i < 8; ++i)
            X[i] = pkfma(c_six, acc[i] + T[i], X[i]);
    }

    // GEMM2 + log_softmax epilogue (packed dot, then wave reduce)
    float l[OUTSZ];
    #pragma unroll
    for (int o = 0; o < OUTSZ; ++o) {
        const float4* w4 = (const float4*)(W2 + (size_t)o * SYS);
        float4 wa0 = w4[lane * 2], wa1 = w4[lane * 2 + 1];
        float4 wc0 = w4[128 + lane * 2], wc1 = w4[129 + lane * 2];
        v2f s2 = mk2(0.f, 0.f);
        s2 = pkfma(X[0], mk2(wa0.x, wc0.x), s2);
        s2 = pkfma(X[1], mk2(wa0.y, wc0.y), s2);
        s2 = pkfma(X[2], mk2(wa0.z, wc0.z), s2);
        s2 = pkfma(X[3], mk2(wa0.w, wc0.w), s2);
        s2 = pkfma(X[4], mk2(wa1.x, wc1.x), s2);
        s2 = pkfma(X[5], mk2(wa1.y, wc1.y), s2);
        s2 = pkfma(X[6], mk2(wa1.z, wc1.z), s2);
        s2 = pkfma(X[7], mk2(wa1.w, wc1.w), s2);
        float s = s2.x + s2.y;
        #pragma unroll
        for (int dlt = 1; dlt < 64; dlt <<= 1) s += __shfl_xor(s, dlt);
        l[o] = s + b2[o];
    }

    float m = l[0];
    #pragma unroll
    for (int o = 1; o < OUTSZ; ++o) m = fmaxf(m, l[o]);
    float ssum = 0.f;
    #pragma unroll
    for (int o = 0; o < OUTSZ; ++o) ssum += __expf(l[o] - m);
    const float lse = m + __logf(ssum);

    float v = l[0] - lse;
    #pragma unroll
    for (int o = 1; o < OUTSZ; ++o)
        if (lane == o) v = l[o] - lse;
    if (lane < OUTSZ)
        out[(size_t)row * OUTSZ + lane] = v;
}

extern "C" void kernel_launch(void* const* d_in, const int* in_sizes, int n_in,
                              void* d_out, int out_size, void* d_ws, size_t ws_size,
                              hipStream_t stream)
{
    const float* x  = (const float*)d_in[0];
    const float* W1 = (const float*)d_in[1];
    const float* b1 = (const float*)d_in[2];
    const float* W2 = (const float*)d_in[3];
    const float* b2 = (const float*)d_in[4];
    float* out = (float*)d_out;
    float* h   = (float*)d_ws;   // 8192*1024*4 = 33.5 MB scratch

    dim3 g1(SYS / BNg, BATCH / BMg);   // 8 x 64 = 512 blocks
    gemm1_kernel<<<g1, 256, 0, stream>>>(x, W1, b1, h);

    rk4_kernel<<<BATCH / 4, 256, 0, stream>>>(h, W2, b2, out);
}